// Round 7
// baseline (2539.009 us; speedup 1.0000x reference)
//
#include <hip/hip_runtime.h>
#include <hip/hip_bf16.h>
#include <stdint.h>

typedef __bf16 bf16x8 __attribute__((ext_vector_type(8)));
typedef float  f32x4  __attribute__((ext_vector_type(4)));

#define MDIM 8192
#define NDIM 4096
#define KDIM 4096
#define BM   256
#define BN   256
#define BK   32
#define NT   (KDIM / BK)   // 128 K-tiles

// ---------------------------------------------------------------- helpers
__device__ __forceinline__ void lds_load16(const void* gsrc, void* ldst) {
    __builtin_amdgcn_global_load_lds(
        (const __attribute__((address_space(1))) unsigned int*)gsrc,
        (__attribute__((address_space(3)))       unsigned int*)ldst,
        16, 0, 0);
}

// ---------------------------------------------------------------- x -> bf16
__global__ __launch_bounds__(256) void cvt_x(const float* __restrict__ X,
                                             __bf16* __restrict__ Xb) {
    size_t t  = (size_t)blockIdx.x * blockDim.x + threadIdx.x;
    size_t i0 = t * 8;
    float4 a = *(const float4*)(X + i0);
    float4 b = *(const float4*)(X + i0 + 4);
    bf16x8 o;
    o[0] = (__bf16)a.x; o[1] = (__bf16)a.y; o[2] = (__bf16)a.z; o[3] = (__bf16)a.w;
    o[4] = (__bf16)b.x; o[5] = (__bf16)b.y; o[6] = (__bf16)b.z; o[7] = (__bf16)b.w;
    *(bf16x8*)(Xb + i0) = o;
}

// ------------------------------------------- Bt[c][k] = d[k]*W[c>>7][k>>7][(k-c)&127]
__global__ __launch_bounds__(256) void build_bt(const float* __restrict__ W,
                                                const float* __restrict__ d,
                                                __bf16* __restrict__ Bt) {
    int t  = blockIdx.x * blockDim.x + threadIdx.x;
    int c  = t >> 9;
    int k0 = (t & 511) * 8;
    int i  = c  >> 7;
    int j  = k0 >> 7;
    const float* wp = W + ((size_t)i * 32 + j) * 128;
    bf16x8 o;
#pragma unroll
    for (int e = 0; e < 8; ++e) {
        int k = k0 + e;
        float v = wp[(k - c) & 127] * d[k];
        o[e] = (__bf16)v;
    }
    *(bf16x8*)(Bt + (size_t)c * KDIM + k0) = o;
}

// ---------------------------------------------------------------- GEMM
// C[M][N] = A[M][K] * Bt[N][K]^T + bias.  256x256 tile, BK=32, 8 waves (2x4),
// 16x16x32 MFMA, 2 phases/K-tile (16 MFMA each), counted vmcnt folded into
// phase 1.  LDS = 2 x 32KB (A 16KB + B 16KB per buffer) -> 64KB total ->
// **2 blocks/CU** (vs 1 at BK=64): cross-block overlap hides barrier/stage
// stalls that in-block scheduling cannot (r4/r5/r6 evidence).
//
// Swizzle (region-local involution, both sides): phys = addr ^
// (((addr>>7)&7)<<4).  Rows are 64B; the XOR spreads a 16-row column-slice
// read over 8 bank-slots (2 lanes each per quarter-wave = free, m136).
// Staged with linear LDS dest + inverse-mapped global source (rule #21).
//
// Stage slots: ph0 -> A(t+1) into buf[1-par] (A(t-1) last read t-1.ph1,
// >=1 barrier + MFMA cluster margin); ph1 -> B(t+2) into buf[par] (B(t)
// last read t.ph0, same margin).
// vmcnt ledger at t.ph1 (2 loads/slot): outstanding = B(t+1)2 [t-1.ph1] +
// A(t+1)2 [t.ph0] + B(t+2)2 [t.ph1] = 6 -> vmcnt(2) completes B(t+1)+A(t+1).
// Tail t = NT-2: B(NT) never staged -> outstanding = B(NT-1)2 + A(NT-1)2,
// newest are A(NT-1) itself -> vmcnt(0) there (round-2 bug class).
__global__ __launch_bounds__(512, 4) void gemm_bc(const __bf16* __restrict__ A,
                                                  const __bf16* __restrict__ Bt,
                                                  const float* __restrict__ bias,
                                                  float* __restrict__ C) {
    __shared__ __align__(16) char lds[2 * 32768];

    // T1: XCD bijective swizzle (grid = 512, divisible by 8)
    const int bid = blockIdx.x;
    const int cpx = gridDim.x >> 3;
    const int swz = (bid & 7) * cpx + (bid >> 3);
    const int ntn = NDIM / BN;                 // 16
    const int brow = (swz / ntn) * BM;
    const int bcol = (swz % ntn) * BN;

    const int tid  = threadIdx.x;
    const int wid  = tid >> 6;
    const int lane = tid & 63;
    const int wr   = wid >> 2;                 // 0..1 -> A half (128 rows)
    const int wc   = wid & 3;                  // 0..3 -> 64-col panel
    const int rlo  = lane & 15;
    const int kg   = lane >> 4;                // 16B slot within 32-k row

    // read-side swizzled addressing:
    // logical(row,kg) = row*64 + kg*16 ; phys = logical ^ (((logical>>7)&7)<<4)
    //   = (row>>1)*128 + (((row&1)*4 + kg) ^ ((row>>1)&7))*16
    // For frag rows R0 + rlo (R0 multiple of 16): (row>>1)&7 = (rlo>>1)&7.
    const int slotA = ((((rlo & 1) << 2) + kg) ^ ((rlo >> 1) & 7)) << 4;
    const int aOff  = wr * 8192 + (rlo >> 1) * 128 + slotA;           // + m*1024
    const int bOff  = 16384 + wc * 4096 + (rlo >> 1) * 128 + slotA;   // + j*1024

    // staging source: thread covers phys LDS bytes o = set*8192 + tid*16;
    // fetch global data for logical = o ^ (((o>>7)&7)<<4)  (involution)
    const int o0 = tid * 16, o1 = 8192 + tid * 16;
    const int l0 = o0 ^ (((o0 >> 7) & 7) << 4);
    const int l1 = o1 ^ (((o1 >> 7) & 7) << 4);
    const int sRow0 = l0 >> 6, sCol0 = ((l0 >> 4) & 3) * 8;   // bf16 units
    const int sRow1 = l1 >> 6, sCol1 = ((l1 >> 4) & 3) * 8;

    const __bf16* Abase = A  + (size_t)brow * KDIM;
    const __bf16* Bbase = Bt + (size_t)bcol * KDIM;

    auto stageA = [&](int t_, int par_) {
        lds_load16(Abase + (size_t)sRow0 * KDIM + t_ * BK + sCol0,
                   lds + par_ * 32768 + 0    + wid * 1024);
        lds_load16(Abase + (size_t)sRow1 * KDIM + t_ * BK + sCol1,
                   lds + par_ * 32768 + 8192 + wid * 1024);
    };
    auto stageB = [&](int t_, int par_) {
        lds_load16(Bbase + (size_t)sRow0 * KDIM + t_ * BK + sCol0,
                   lds + par_ * 32768 + 16384 + 0    + wid * 1024);
        lds_load16(Bbase + (size_t)sRow1 * KDIM + t_ * BK + sCol1,
                   lds + par_ * 32768 + 16384 + 8192 + wid * 1024);
    };

    f32x4 acc[8][4];
#pragma unroll
    for (int i = 0; i < 8; ++i)
#pragma unroll
        for (int j = 0; j < 4; ++j) acc[i][j] = (f32x4)0.0f;

    // prologue: A(0),B(0) -> buf0 ; B(1) -> buf1.  vmcnt(2) completes
    // A(0),B(0), keeps B(1) in flight (matches steady-state entry).
    stageA(0, 0); stageB(0, 0);
    stageB(1, 1);
    asm volatile("s_waitcnt vmcnt(2)" ::: "memory");
    __builtin_amdgcn_s_barrier();

#pragma unroll 2
    for (int t = 0; t < NT; ++t) {
        const int par = t & 1;
        const char* buf = lds + par * 32768;

        // ---- phase 0: read B j0-3 + A m0-3 ; stage A(t+1)
        bf16x8 bfr[4], am[4];
#pragma unroll
        for (int j = 0; j < 4; ++j)
            bfr[j] = *(const bf16x8*)(buf + bOff + j * 1024);
#pragma unroll
        for (int m = 0; m < 4; ++m)
            am[m] = *(const bf16x8*)(buf + aOff + m * 1024);
        if (t + 1 < NT) stageA(t + 1, 1 - par);
        __builtin_amdgcn_s_barrier();
        asm volatile("s_waitcnt lgkmcnt(0)" ::: "memory");
        __builtin_amdgcn_s_setprio(1);
#pragma unroll
        for (int m = 0; m < 4; ++m)
#pragma unroll
            for (int j = 0; j < 4; ++j)
                acc[m][j] = __builtin_amdgcn_mfma_f32_16x16x32_bf16(am[m], bfr[j], acc[m][j], 0, 0, 0);
        __builtin_amdgcn_s_setprio(0);

        // ---- phase 1: read A m4-7 ; stage B(t+2) ; folded boundary vmcnt
        bf16x8 am2[4];
#pragma unroll
        for (int m = 0; m < 4; ++m)
            am2[m] = *(const bf16x8*)(buf + aOff + (4 + m) * 1024);
        if (t + 2 < NT) stageB(t + 2, par);
        if (t < NT - 2) { asm volatile("s_waitcnt vmcnt(2)" ::: "memory"); }
        else            { asm volatile("s_waitcnt vmcnt(0)" ::: "memory"); }
        __builtin_amdgcn_s_barrier();
        asm volatile("s_waitcnt lgkmcnt(0)" ::: "memory");
        __builtin_amdgcn_s_setprio(1);
#pragma unroll
        for (int m = 0; m < 4; ++m)
#pragma unroll
            for (int j = 0; j < 4; ++j)
                acc[4 + m][j] = __builtin_amdgcn_mfma_f32_16x16x32_bf16(am2[m], bfr[j], acc[4 + m][j], 0, 0, 0);
        __builtin_amdgcn_s_setprio(0);
    }

    // epilogue: D layout col=lane&15, row=(lane>>4)*4+reg  [m89]
#pragma unroll
    for (int j = 0; j < 4; ++j) {
        const int col = bcol + wc * 64 + j * 16 + rlo;
        const float bs = bias[col];
#pragma unroll
        for (int i = 0; i < 8; ++i) {
            const int row = brow + wr * 128 + i * 16 + kg * 4;
#pragma unroll
            for (int r = 0; r < 4; ++r)
                C[(size_t)(row + r) * NDIM + col] = acc[i][j][r] + bs;
        }
    }
}

// ---------------------------------------------------------------- launch
extern "C" void kernel_launch(void* const* d_in, const int* in_sizes, int n_in,
                              void* d_out, int out_size, void* d_ws, size_t ws_size,
                              hipStream_t stream) {
    const float* x    = (const float*)d_in[0];
    const float* W    = (const float*)d_in[1];
    const float* d    = (const float*)d_in[2];
    const float* bias = (const float*)d_in[3];
    float* y = (float*)d_out;

    __bf16* Xb = (__bf16*)d_ws;                                    // 64 MiB
    __bf16* Bt = (__bf16*)((char*)d_ws + (size_t)MDIM * KDIM * 2); // 32 MiB

    cvt_x<<<(MDIM * (size_t)KDIM) / 8 / 256, 256, 0, stream>>>(x, Xb);
    build_bt<<<(NDIM * KDIM) / 8 / 256, 256, 0, stream>>>(W, d, Bt);
    gemm_bc<<<(MDIM / BM) * (NDIM / BN), 512, 0, stream>>>(Xb, Bt, bias, y);
}

// Round 9
// 282.417 us; speedup vs baseline: 8.9903x; 8.9903x over previous
//
#include <hip/hip_runtime.h>
#include <hip/hip_bf16.h>
#include <stdint.h>

typedef __bf16 bf16x8 __attribute__((ext_vector_type(8)));
typedef float  f32x4  __attribute__((ext_vector_type(4)));

#define MDIM 8192
#define NDIM 4096
#define KDIM 4096
#define BM   256
#define BN   256
#define BK   64
#define NT   (KDIM / BK)   // 64 K-tiles

// ---------------------------------------------------------------- helpers
__device__ __forceinline__ void lds_load16(const void* gsrc, void* ldst) {
    __builtin_amdgcn_global_load_lds(
        (const __attribute__((address_space(1))) unsigned int*)gsrc,
        (__attribute__((address_space(3)))       unsigned int*)ldst,
        16, 0, 0);
}

// ---------------------------------------------------------------- x -> bf16
__global__ __launch_bounds__(256) void cvt_x(const float* __restrict__ X,
                                             __bf16* __restrict__ Xb) {
    size_t t  = (size_t)blockIdx.x * blockDim.x + threadIdx.x;
    size_t i0 = t * 8;
    float4 a = *(const float4*)(X + i0);
    float4 b = *(const float4*)(X + i0 + 4);
    bf16x8 o;
    o[0] = (__bf16)a.x; o[1] = (__bf16)a.y; o[2] = (__bf16)a.z; o[3] = (__bf16)a.w;
    o[4] = (__bf16)b.x; o[5] = (__bf16)b.y; o[6] = (__bf16)b.z; o[7] = (__bf16)b.w;
    *(bf16x8*)(Xb + i0) = o;
}

// ------------------------------------------- Bt[c][k] = d[k]*W[c>>7][k>>7][(k-c)&127]
__global__ __launch_bounds__(256) void build_bt(const float* __restrict__ W,
                                                const float* __restrict__ d,
                                                __bf16* __restrict__ Bt) {
    int t  = blockIdx.x * blockDim.x + threadIdx.x;
    int c  = t >> 9;
    int k0 = (t & 511) * 8;
    int i  = c  >> 7;
    int j  = k0 >> 7;
    const float* wp = W + ((size_t)i * 32 + j) * 128;
    bf16x8 o;
#pragma unroll
    for (int e = 0; e < 8; ++e) {
        int k = k0 + e;
        float v = wp[(k - c) & 127] * d[k];
        o[e] = (__bf16)v;
    }
    *(bf16x8*)(Bt + (size_t)c * KDIM + k0) = o;
}

// ---------------------------------------------------------------- GEMM
// C[M][N] = A[M][K] * Bt[N][K]^T + bias.  256x256 tile, BK=64, 8 waves (2x4),
// 16x16x32 MFMA.  r3 structure with the boundary {vmcnt; barrier} FOLDED into
// phase 3 (4 barrier events/K-tile instead of 5).  To keep DMA-overwrite
// safety with the fold, stage slots are rotated one phase later than r3:
//   ph0: B(t+1).hi -> buf[1-par]   (region last read t-1.ph0, certified
//        <= t-1.ph1 barrier entry; issue after exiting t-1.ph3 barrier)
//   ph1: A(t+1).lo -> buf[1-par]   (A(t-1) reads certified <= t.ph0 entry;
//        issue after exiting t.ph0 barrier)
//   ph2: A(t+1).hi -> buf[1-par]
//   ph3: B(t+2).lo -> buf[par]     (B(t) frags certified <= t.ph1 entry)
// vmcnt ledger at t.ph3 (before its barrier): outstanding =
//   B(t+1).lo[t-1.ph3] + B(t+1).hi[t.ph0] + A(t+1).lo[ph1] + A(t+1).hi[ph2]
//   + B(t+2).lo[ph3] = 10 -> vmcnt(2) completes B(t+1)+A(t+1), keeps
//   B(t+2).lo.  Tail t >= NT-2: stages skipped, newest outstanding are
//   needed -> vmcnt(0).
// (NOTE r8 post-mortem: any scheme that leaves A(t).hi uncertified at t.ph0
//  is WRONG -- wr=1 waves read the A.hi region in every phase.)
__global__ __launch_bounds__(512, 2) void gemm_bc(const __bf16* __restrict__ A,
                                                  const __bf16* __restrict__ Bt,
                                                  const float* __restrict__ bias,
                                                  float* __restrict__ C) {
    __shared__ __align__(16) char lds[2 * 65536];

    // T1: XCD bijective swizzle (grid = 512, divisible by 8)
    const int bid = blockIdx.x;
    const int cpx = gridDim.x >> 3;
    const int swz = (bid & 7) * cpx + (bid >> 3);
    const int ntn = NDIM / BN;                 // 16
    const int brow = (swz / ntn) * BM;
    const int bcol = (swz % ntn) * BN;

    const int tid  = threadIdx.x;
    const int wid  = tid >> 6;
    const int lane = tid & 63;
    const int wr   = wid >> 2;                 // 0..1 -> A half
    const int wc   = wid & 3;                  // 0..3 -> 64-col panel
    const int rlo  = lane & 15;
    const int kg   = lane >> 4;

    // ds_read addressing (T2 swizzle on the k-offset within each 128B row)
    const int xorK = (rlo & 7) << 4;
    const int kb0  = ((kg * 16)      ^ xorK);
    const int kb1  = ((64 + kg * 16) ^ xorK);
    const char* bufA0 = lds + wr * 16384 + rlo * 128;
    const char* bufB0 = lds + 32768 + (wc >> 1) * 16384 + ((wc & 1) * 64 + rlo) * 128;

    // staging source (pre-swizzled global col so linear LDS dest == swizzled)
    const int sRow = wid * 8 + (lane >> 3);
    const int sCol = 8 * ((lane & 7) ^ ((lane >> 3) & 7));

    const __bf16* Abase = A  + (size_t)brow * KDIM;
    const __bf16* Bbase = Bt + (size_t)bcol * KDIM;

    auto stageA = [&](int t_, int half, int par_) {
#pragma unroll
        for (int l = 0; l < 2; ++l) {
            const __bf16* gp = Abase + (size_t)(half * 128 + l * 64 + sRow) * KDIM
                               + t_ * 64 + sCol;
            lds_load16(gp, lds + par_ * 65536 + half * 16384 + l * 8192 + wid * 1024);
        }
    };
    auto stageB = [&](int t_, int half, int par_) {
#pragma unroll
        for (int l = 0; l < 2; ++l) {
            const __bf16* gp = Bbase + (size_t)(half * 128 + l * 64 + sRow) * KDIM
                               + t_ * 64 + sCol;
            lds_load16(gp, lds + par_ * 65536 + 32768 + half * 16384 + l * 8192 + wid * 1024);
        }
    };

    f32x4 acc[8][4];
#pragma unroll
    for (int i = 0; i < 8; ++i)
#pragma unroll
        for (int j = 0; j < 4; ++j) acc[i][j] = (f32x4)0.0f;

    // prologue: A(0),B(0) -> buf0 ; B(1).lo -> buf1 (B(1).hi comes from the
    // t=0 ph0 slot).  vmcnt(2) completes A(0),B(0), keeps B(1).lo in flight.
    stageA(0, 0, 0); stageA(0, 1, 0);
    stageB(0, 0, 0); stageB(0, 1, 0);
    stageB(1, 0, 1);
    asm volatile("s_waitcnt vmcnt(2)" ::: "memory");
    __builtin_amdgcn_s_barrier();

    bf16x8 bf[4][2];   // B fragments, live across the whole K-tile

#define MFMA16(q)                                                                   \
    _Pragma("unroll")                                                               \
    for (int j = 0; j < 4; ++j) {                                                   \
        acc[(q)*2+0][j] = __builtin_amdgcn_mfma_f32_16x16x32_bf16(a00, bf[j][0], acc[(q)*2+0][j], 0, 0, 0); \
        acc[(q)*2+0][j] = __builtin_amdgcn_mfma_f32_16x16x32_bf16(a01, bf[j][1], acc[(q)*2+0][j], 0, 0, 0); \
        acc[(q)*2+1][j] = __builtin_amdgcn_mfma_f32_16x16x32_bf16(a10, bf[j][0], acc[(q)*2+1][j], 0, 0, 0); \
        acc[(q)*2+1][j] = __builtin_amdgcn_mfma_f32_16x16x32_bf16(a11, bf[j][1], acc[(q)*2+1][j], 0, 0, 0); \
    }

#define READ_A(q)                                                                   \
    bf16x8 a00 = *(const bf16x8*)(bufA + (q) * 4096 +    0 + kb0);                  \
    bf16x8 a01 = *(const bf16x8*)(bufA + (q) * 4096 +    0 + kb1);                  \
    bf16x8 a10 = *(const bf16x8*)(bufA + (q) * 4096 + 2048 + kb0);                  \
    bf16x8 a11 = *(const bf16x8*)(bufA + (q) * 4096 + 2048 + kb1);

#pragma unroll 2
    for (int t = 0; t < NT; ++t) {
        const int par = t & 1;
        const char* bufA = bufA0 + par * 65536;
        const char* bufB = bufB0 + par * 65536;

        // ---- phase 0: 8 B-frag reads + A quad0 ; stage B(t+1).hi
        {
#pragma unroll
            for (int j = 0; j < 4; ++j) {
                bf[j][0] = *(const bf16x8*)(bufB + j * 2048 + kb0);
                bf[j][1] = *(const bf16x8*)(bufB + j * 2048 + kb1);
            }
            READ_A(0)
            if (t + 1 < NT) stageB(t + 1, 1, 1 - par);
            __builtin_amdgcn_s_barrier();
            asm volatile("s_waitcnt lgkmcnt(0)" ::: "memory");
            __builtin_amdgcn_s_setprio(1);
            MFMA16(0)
            __builtin_amdgcn_s_setprio(0);
        }
        // ---- phase 1: A quad1 ; stage A(t+1).lo
        {
            READ_A(1)
            if (t + 1 < NT) stageA(t + 1, 0, 1 - par);
            __builtin_amdgcn_s_barrier();
            asm volatile("s_waitcnt lgkmcnt(0)" ::: "memory");
            __builtin_amdgcn_s_setprio(1);
            MFMA16(1)
            __builtin_amdgcn_s_setprio(0);
        }
        // ---- phase 2: A quad2 ; stage A(t+1).hi
        {
            READ_A(2)
            if (t + 1 < NT) stageA(t + 1, 1, 1 - par);
            __builtin_amdgcn_s_barrier();
            asm volatile("s_waitcnt lgkmcnt(0)" ::: "memory");
            __builtin_amdgcn_s_setprio(1);
            MFMA16(2)
            __builtin_amdgcn_s_setprio(0);
        }
        // ---- phase 3: A quad3 ; stage B(t+2).lo ; folded boundary vmcnt
        {
            READ_A(3)
            if (t + 2 < NT) stageB(t + 2, 0, par);
            if (t < NT - 2) { asm volatile("s_waitcnt vmcnt(2)" ::: "memory"); }
            else            { asm volatile("s_waitcnt vmcnt(0)" ::: "memory"); }
            __builtin_amdgcn_s_barrier();
            asm volatile("s_waitcnt lgkmcnt(0)" ::: "memory");
            __builtin_amdgcn_s_setprio(1);
            MFMA16(3)
            __builtin_amdgcn_s_setprio(0);
        }
    }
#undef MFMA16
#undef READ_A

    // epilogue: D layout col=lane&15, row=(lane>>4)*4+reg  [m89]
#pragma unroll
    for (int j = 0; j < 4; ++j) {
        const int col = bcol + wc * 64 + j * 16 + rlo;
        const float bs = bias[col];
#pragma unroll
        for (int i = 0; i < 8; ++i) {
            const int row = brow + wr * 128 + i * 16 + kg * 4;
#pragma unroll
            for (int r = 0; r < 4; ++r)
                C[(size_t)(row + r) * NDIM + col] = acc[i][j][r] + bs;
        }
    }
}

// ---------------------------------------------------------------- launch
extern "C" void kernel_launch(void* const* d_in, const int* in_sizes, int n_in,
                              void* d_out, int out_size, void* d_ws, size_t ws_size,
                              hipStream_t stream) {
    const float* x    = (const float*)d_in[0];
    const float* W    = (const float*)d_in[1];
    const float* d    = (const float*)d_in[2];
    const float* bias = (const float*)d_in[3];
    float* y = (float*)d_out;

    __bf16* Xb = (__bf16*)d_ws;                                    // 64 MiB
    __bf16* Bt = (__bf16*)((char*)d_ws + (size_t)MDIM * KDIM * 2); // 32 MiB

    cvt_x<<<(MDIM * (size_t)KDIM) / 8 / 256, 256, 0, stream>>>(x, Xb);
    build_bt<<<(NDIM * KDIM) / 8 / 256, 256, 0, stream>>>(W, d, Bt);
    gemm_bc<<<(MDIM / BM) * (NDIM / BN), 512, 0, stream>>>(Xb, Bt, bias, y);
}

// Round 10
// 281.551 us; speedup vs baseline: 9.0179x; 1.0031x over previous
//
#include <hip/hip_runtime.h>
#include <hip/hip_bf16.h>
#include <stdint.h>

typedef __bf16 bf16x8 __attribute__((ext_vector_type(8)));
typedef float  f32x4  __attribute__((ext_vector_type(4)));

#define MDIM 8192
#define NDIM 4096
#define KDIM 4096
#define BM   256
#define BN   256
#define BK   64
#define NT   (KDIM / BK)   // 64 K-tiles

// ---------------------------------------------------------------- helpers
__device__ __forceinline__ void lds_load16(const void* gsrc, void* ldst) {
    __builtin_amdgcn_global_load_lds(
        (const __attribute__((address_space(1))) unsigned int*)gsrc,
        (__attribute__((address_space(3)))       unsigned int*)ldst,
        16, 0, 0);
}

// ---------------------------------------------------------------- x -> bf16
__global__ __launch_bounds__(256) void cvt_x(const float* __restrict__ X,
                                             __bf16* __restrict__ Xb) {
    size_t t  = (size_t)blockIdx.x * blockDim.x + threadIdx.x;
    size_t i0 = t * 8;
    float4 a = *(const float4*)(X + i0);
    float4 b = *(const float4*)(X + i0 + 4);
    bf16x8 o;
    o[0] = (__bf16)a.x; o[1] = (__bf16)a.y; o[2] = (__bf16)a.z; o[3] = (__bf16)a.w;
    o[4] = (__bf16)b.x; o[5] = (__bf16)b.y; o[6] = (__bf16)b.z; o[7] = (__bf16)b.w;
    *(bf16x8*)(Xb + i0) = o;
}

// ------------------------------------------- Bt[c][k] = d[k]*W[c>>7][k>>7][(k-c)&127]
__global__ __launch_bounds__(256) void build_bt(const float* __restrict__ W,
                                                const float* __restrict__ d,
                                                __bf16* __restrict__ Bt) {
    int t  = blockIdx.x * blockDim.x + threadIdx.x;
    int c  = t >> 9;
    int k0 = (t & 511) * 8;
    int i  = c  >> 7;
    int j  = k0 >> 7;
    const float* wp = W + ((size_t)i * 32 + j) * 128;
    bf16x8 o;
#pragma unroll
    for (int e = 0; e < 8; ++e) {
        int k = k0 + e;
        float v = wp[(k - c) & 127] * d[k];
        o[e] = (__bf16)v;
    }
    *(bf16x8*)(Bt + (size_t)c * KDIM + k0) = o;
}

// ---------------------------------------------------------------- GEMM
// C[M][N] = A[M][K] * Bt[N][K]^T + bias.  256x256 tile, BK=64, 8 waves (2x4),
// 16x16x32 MFMA, 4 single-barrier phases/K-tile (r6 structure) with the
// stage slots re-packed so EVERY DMA load has >=2 phases between issue and
// its certifying vmcnt (r6's weakest margin was A(t+1).hi: issued ph2,
// certified ph3 = 1 phase < HBM latency):
//   ph0: (no stage)                ph1: A(t+1).lo+hi -> buf[1-par]
//   ph2: B(t+2).lo -> buf[par]     ph3: B(t+2).hi -> buf[par], vmcnt, barrier
// Overwrite safety (per slot):
//   ph1 A slots: A(t-1)'s last ds_reads are certified by each wave's
//     t-1.ph3 lgkmcnt(0), which precedes its t.ph0-barrier arrival; the
//     ph1 DMA issues after exiting that barrier => happens-after.  SAFE.
//   ph2/ph3 B slots: B(t)'s ph0 reads certified by t.ph0 lgkmcnt(0)
//     before each wave's t.ph1-barrier arrival; DMAs issue after exiting
//     ph1/ph2 barriers => >=2 certified barriers.  SAFE.
// vmcnt ledger (2 loads/slot; induction: entering t.ph0 outstanding =
// B(t+1)x4): at t.ph3 after issue, queue = [B(t+1)x4, A(t+1)x4, B(t+2)x4]
// = 12 -> vmcnt(4) retires B(t+1)+A(t+1) (both read at t+1.ph0), keeps
// B(t+2).  Margins: A.lo/hi = 2 phases, B.hi = 4, B.lo = 5.
// Tail: t = NT-2: B(NT) never staged -> queue = [B(NT-1)x4, A(NT-1)x4] = 8,
// newest 4 are A(NT-1) itself -> vmcnt(0) (round-2/7/8 bug class).
// t = NT-1: nothing outstanding; vmcnt(0) harmless.
__global__ __launch_bounds__(512, 2) void gemm_bc(const __bf16* __restrict__ A,
                                                  const __bf16* __restrict__ Bt,
                                                  const float* __restrict__ bias,
                                                  float* __restrict__ C) {
    __shared__ __align__(16) char lds[2 * 65536];

    // T1: XCD bijective swizzle (grid = 512, divisible by 8)
    const int bid = blockIdx.x;
    const int cpx = gridDim.x >> 3;
    const int swz = (bid & 7) * cpx + (bid >> 3);
    const int ntn = NDIM / BN;                 // 16
    const int brow = (swz / ntn) * BM;
    const int bcol = (swz % ntn) * BN;

    const int tid  = threadIdx.x;
    const int wid  = tid >> 6;
    const int lane = tid & 63;
    const int wr   = wid >> 2;                 // 0..1 -> A half
    const int wc   = wid & 3;                  // 0..3 -> 64-col panel
    const int rlo  = lane & 15;
    const int kg   = lane >> 4;

    // ds_read addressing (T2 swizzle on the k-offset within each 128B row)
    const int xorK = (rlo & 7) << 4;
    const int kb0  = ((kg * 16)      ^ xorK);
    const int kb1  = ((64 + kg * 16) ^ xorK);
    const char* bufA0 = lds + wr * 16384 + rlo * 128;
    const char* bufB0 = lds + 32768 + (wc >> 1) * 16384 + ((wc & 1) * 64 + rlo) * 128;

    // staging source (pre-swizzled global col so linear LDS dest == swizzled)
    const int sRow = wid * 8 + (lane >> 3);
    const int sCol = 8 * ((lane & 7) ^ ((lane >> 3) & 7));

    const __bf16* Abase = A  + (size_t)brow * KDIM;
    const __bf16* Bbase = Bt + (size_t)bcol * KDIM;

    auto stageA = [&](int t_, int half, int par_) {
#pragma unroll
        for (int l = 0; l < 2; ++l) {
            const __bf16* gp = Abase + (size_t)(half * 128 + l * 64 + sRow) * KDIM
                               + t_ * 64 + sCol;
            lds_load16(gp, lds + par_ * 65536 + half * 16384 + l * 8192 + wid * 1024);
        }
    };
    auto stageB = [&](int t_, int half, int par_) {
#pragma unroll
        for (int l = 0; l < 2; ++l) {
            const __bf16* gp = Bbase + (size_t)(half * 128 + l * 64 + sRow) * KDIM
                               + t_ * 64 + sCol;
            lds_load16(gp, lds + par_ * 65536 + 32768 + half * 16384 + l * 8192 + wid * 1024);
        }
    };

    f32x4 acc[8][4];
#pragma unroll
    for (int i = 0; i < 8; ++i)
#pragma unroll
        for (int j = 0; j < 4; ++j) acc[i][j] = (f32x4)0.0f;

    // prologue: B(0), A(0) -> buf0 ; B(1) (both halves) -> buf1 = 12 loads.
    // vmcnt(4) retires B(0)+A(0) (read at t=0.ph0), keeps B(1)x4 in flight
    // == induction state entering t=0.ph0.
    stageB(0, 0, 0); stageB(0, 1, 0);
    stageA(0, 0, 0); stageA(0, 1, 0);
    stageB(1, 0, 1); stageB(1, 1, 1);
    asm volatile("s_waitcnt vmcnt(4)" ::: "memory");
    __builtin_amdgcn_s_barrier();

    bf16x8 bf[4][2];   // B fragments, live across the whole K-tile

#define MFMA16(q)                                                                   \
    _Pragma("unroll")                                                               \
    for (int j = 0; j < 4; ++j) {                                                   \
        acc[(q)*2+0][j] = __builtin_amdgcn_mfma_f32_16x16x32_bf16(a00, bf[j][0], acc[(q)*2+0][j], 0, 0, 0); \
        acc[(q)*2+0][j] = __builtin_amdgcn_mfma_f32_16x16x32_bf16(a01, bf[j][1], acc[(q)*2+0][j], 0, 0, 0); \
        acc[(q)*2+1][j] = __builtin_amdgcn_mfma_f32_16x16x32_bf16(a10, bf[j][0], acc[(q)*2+1][j], 0, 0, 0); \
        acc[(q)*2+1][j] = __builtin_amdgcn_mfma_f32_16x16x32_bf16(a11, bf[j][1], acc[(q)*2+1][j], 0, 0, 0); \
    }

#define READ_A(q)                                                                   \
    bf16x8 a00 = *(const bf16x8*)(bufA + (q) * 4096 +    0 + kb0);                  \
    bf16x8 a01 = *(const bf16x8*)(bufA + (q) * 4096 +    0 + kb1);                  \
    bf16x8 a10 = *(const bf16x8*)(bufA + (q) * 4096 + 2048 + kb0);                  \
    bf16x8 a11 = *(const bf16x8*)(bufA + (q) * 4096 + 2048 + kb1);

#pragma unroll 2
    for (int t = 0; t < NT; ++t) {
        const int par = t & 1;
        const char* bufA = bufA0 + par * 65536;
        const char* bufB = bufB0 + par * 65536;

        // ---- phase 0: 8 B-frag reads + A quad0 ; no stage
        {
#pragma unroll
            for (int j = 0; j < 4; ++j) {
                bf[j][0] = *(const bf16x8*)(bufB + j * 2048 + kb0);
                bf[j][1] = *(const bf16x8*)(bufB + j * 2048 + kb1);
            }
            READ_A(0)
            __builtin_amdgcn_s_barrier();
            asm volatile("s_waitcnt lgkmcnt(0)" ::: "memory");
            __builtin_amdgcn_s_setprio(1);
            MFMA16(0)
            __builtin_amdgcn_s_setprio(0);
        }
        // ---- phase 1: A quad1 ; stage A(t+1).lo + A(t+1).hi
        {
            READ_A(1)
            if (t + 1 < NT) { stageA(t + 1, 0, 1 - par); stageA(t + 1, 1, 1 - par); }
            __builtin_amdgcn_s_barrier();
            asm volatile("s_waitcnt lgkmcnt(0)" ::: "memory");
            __builtin_amdgcn_s_setprio(1);
            MFMA16(1)
            __builtin_amdgcn_s_setprio(0);
        }
        // ---- phase 2: A quad2 ; stage B(t+2).lo
        {
            READ_A(2)
            if (t + 2 < NT) stageB(t + 2, 0, par);
            __builtin_amdgcn_s_barrier();
            asm volatile("s_waitcnt lgkmcnt(0)" ::: "memory");
            __builtin_amdgcn_s_setprio(1);
            MFMA16(2)
            __builtin_amdgcn_s_setprio(0);
        }
        // ---- phase 3: A quad3 ; stage B(t+2).hi ; folded boundary vmcnt
        {
            READ_A(3)
            if (t + 2 < NT) stageB(t + 2, 1, par);
            if (t < NT - 2) { asm volatile("s_waitcnt vmcnt(4)" ::: "memory"); }
            else            { asm volatile("s_waitcnt vmcnt(0)" ::: "memory"); }
            __builtin_amdgcn_s_barrier();
            asm volatile("s_waitcnt lgkmcnt(0)" ::: "memory");
            __builtin_amdgcn_s_setprio(1);
            MFMA16(3)
            __builtin_amdgcn_s_setprio(0);
        }
    }
#undef MFMA16
#undef READ_A

    // epilogue: D layout col=lane&15, row=(lane>>4)*4+reg  [m89]
#pragma unroll
    for (int j = 0; j < 4; ++j) {
        const int col = bcol + wc * 64 + j * 16 + rlo;
        const float bs = bias[col];
#pragma unroll
        for (int i = 0; i < 8; ++i) {
            const int row = brow + wr * 128 + i * 16 + kg * 4;
#pragma unroll
            for (int r = 0; r < 4; ++r)
                C[(size_t)(row + r) * NDIM + col] = acc[i][j][r] + bs;
        }
    }
}

// ---------------------------------------------------------------- launch
extern "C" void kernel_launch(void* const* d_in, const int* in_sizes, int n_in,
                              void* d_out, int out_size, void* d_ws, size_t ws_size,
                              hipStream_t stream) {
    const float* x    = (const float*)d_in[0];
    const float* W    = (const float*)d_in[1];
    const float* d    = (const float*)d_in[2];
    const float* bias = (const float*)d_in[3];
    float* y = (float*)d_out;

    __bf16* Xb = (__bf16*)d_ws;                                    // 64 MiB
    __bf16* Bt = (__bf16*)((char*)d_ws + (size_t)MDIM * KDIM * 2); // 32 MiB

    cvt_x<<<(MDIM * (size_t)KDIM) / 8 / 256, 256, 0, stream>>>(x, Xb);
    build_bt<<<(NDIM * KDIM) / 8 / 256, 256, 0, stream>>>(W, d, Bt);
    gemm_bc<<<(MDIM / BM) * (NDIM / BN), 512, 0, stream>>>(Xb, Bt, bias, y);
}